// Round 1
// baseline (83.157 us; speedup 1.0000x reference)
//
#include <hip/hip_runtime.h>

// Problem constants (fixed by the reference): B=2, S=4, N=M=4096, 3D fp32 points.
constexpr int Bn = 2;
constexpr int Sn = 4;
constexpr int Nn = 4096;
constexpr int Mn = 4096;
constexpr int NSLICE = Bn * Sn;      // 8 (b,s) slices, slice l = b*S + s
constexpr int TILE = 256;            // A-points per block
constexpr int NT = Nn / TILE;        // 16 tiles per (dir, slice)

// ws layout: float ws[2][NSLICE][NT]  (per-direction, per-slice, per-tile partial sums of min-dist)

__global__ __launch_bounds__(256) void chamfer_min_kernel(
    const float* __restrict__ X,   // output_points  [NSLICE][Nn][3]
    const float* __restrict__ Y,   // target_points  [NSLICE][Mn][3]
    float* __restrict__ ws)
{
    // Full opposing cloud in LDS as float4 (16B aligned -> single ds_read_b128 broadcast per point)
    __shared__ float4 ldsB[Mn];    // 64 KB

    const int tile  = blockIdx.x;
    const int slice = blockIdx.y;
    const int dir   = blockIdx.z;  // 0: A=X,B=Y (dist1) ; 1: A=Y,B=X (dist2)

    const float* A  = (dir == 0 ? X : Y) + slice * (Nn * 3);
    const float* Bp = (dir == 0 ? Y : X) + slice * (Mn * 3);

    const int tid = threadIdx.x;

    // Stage B cloud into LDS
    for (int p = tid; p < Mn; p += 256) {
        float bx = Bp[p * 3 + 0];
        float by = Bp[p * 3 + 1];
        float bz = Bp[p * 3 + 2];
        ldsB[p] = make_float4(bx, by, bz, 0.0f);
    }
    __syncthreads();

    const int n = tile * TILE + tid;
    const float ax = A[n * 3 + 0];
    const float ay = A[n * 3 + 1];
    const float az = A[n * 3 + 2];

    // Two accumulators to break the serial min dependency chain; fminf(fminf(...)) -> v_min3_f32
    float m0 = 3.4e38f;
    float m1 = 3.4e38f;

    #pragma unroll 8
    for (int m = 0; m < Mn; m += 4) {
        float4 b0 = ldsB[m + 0];
        float4 b1 = ldsB[m + 1];
        float4 b2 = ldsB[m + 2];
        float4 b3 = ldsB[m + 3];

        float dx0 = ax - b0.x, dy0 = ay - b0.y, dz0 = az - b0.z;
        float d0  = dx0 * dx0 + dy0 * dy0 + dz0 * dz0;
        float dx1 = ax - b1.x, dy1 = ay - b1.y, dz1 = az - b1.z;
        float d1  = dx1 * dx1 + dy1 * dy1 + dz1 * dz1;
        float dx2 = ax - b2.x, dy2 = ay - b2.y, dz2 = az - b2.z;
        float d2  = dx2 * dx2 + dy2 * dy2 + dz2 * dz2;
        float dx3 = ax - b3.x, dy3 = ay - b3.y, dz3 = az - b3.z;
        float d3  = dx3 * dx3 + dy3 * dy3 + dz3 * dz3;

        m0 = fminf(fminf(m0, d0), d1);
        m1 = fminf(fminf(m1, d2), d3);
    }

    float mind = fminf(m0, m1);

    // Block-level sum of the 256 min-distances (deterministic: shuffle tree + fixed-order wave combine)
    float s = mind;
    s += __shfl_down(s, 32);
    s += __shfl_down(s, 16);
    s += __shfl_down(s, 8);
    s += __shfl_down(s, 4);
    s += __shfl_down(s, 2);
    s += __shfl_down(s, 1);

    // Reuse LDS for the 4 per-wave partials (all waves are done reading ldsB)
    __syncthreads();
    float* red = (float*)ldsB;
    if ((tid & 63) == 0) red[tid >> 6] = s;
    __syncthreads();

    if (tid == 0) {
        float bs = red[0] + red[1] + red[2] + red[3];
        ws[(dir * NSLICE + slice) * NT + tile] = bs;
    }
}

__global__ __launch_bounds__(64) void chamfer_finalize(
    const float* __restrict__ ws, float* __restrict__ out)
{
    const int tid = threadIdx.x;
    // out[0..3]  = chamfer_distances[s]          (mean over b of combined[b][s])
    // out[4..11] = chamfer_distances_tensor[s][b] = combined[b][s], combined = mean(dist1)+mean(dist2)
    if (tid < 8) {
        const int s = tid >> 1, b = tid & 1;
        const int l = b * Sn + s;
        float s1 = 0.0f, s2 = 0.0f;
        for (int i = 0; i < NT; ++i) s1 += ws[(0 * NSLICE + l) * NT + i];
        for (int i = 0; i < NT; ++i) s2 += ws[(1 * NSLICE + l) * NT + i];
        out[4 + s * 2 + b] = s1 * (1.0f / Nn) + s2 * (1.0f / Mn);
    } else if (tid < 12) {
        const int s = tid - 8;
        float c[2];
        for (int b = 0; b < 2; ++b) {
            const int l = b * Sn + s;
            float s1 = 0.0f, s2 = 0.0f;
            for (int i = 0; i < NT; ++i) s1 += ws[(0 * NSLICE + l) * NT + i];
            for (int i = 0; i < NT; ++i) s2 += ws[(1 * NSLICE + l) * NT + i];
            c[b] = s1 * (1.0f / Nn) + s2 * (1.0f / Mn);
        }
        out[s] = 0.5f * (c[0] + c[1]);
    }
}

extern "C" void kernel_launch(void* const* d_in, const int* in_sizes, int n_in,
                              void* d_out, int out_size, void* d_ws, size_t ws_size,
                              hipStream_t stream) {
    const float* X = (const float*)d_in[0];   // output_points [2,4,4096,3]
    const float* Y = (const float*)d_in[1];   // target_points [2,4,4096,3]
    float* out = (float*)d_out;               // 12 floats: [4] cd + [4,2] tensor
    float* ws  = (float*)d_ws;                // 2*8*16 floats of partials

    dim3 grid(NT, NSLICE, 2);
    chamfer_min_kernel<<<grid, 256, 0, stream>>>(X, Y, ws);
    chamfer_finalize<<<1, 64, 0, stream>>>(ws, out);
}

// Round 2
// 66.992 us; speedup vs baseline: 1.2413x; 1.2413x over previous
//
#include <hip/hip_runtime.h>

// Problem constants: B=2, S=4, N=M=4096, fp32 3D points.
constexpr int Bn = 2;
constexpr int Sn = 4;
constexpr int Nn = 4096;
constexpr int Mn = 4096;
constexpr int NS2 = 16;               // (dir,slice) pairs: z = dir*8 + slice
constexpr int ATILE = 1024;           // A-points per block (4 per thread)
constexpr int BCHUNK = 1024;          // B-points staged in LDS (16 KB)
constexpr int NAT = Nn / ATILE;       // 4
constexpr int NBC = Mn / BCHUNK;      // 4
constexpr int APT = ATILE / 256;      // 4 A-points per thread

// ws layout: float pmin[NS2][NBC][Nn]  (1 MB)  followed by float sums[NS2]
constexpr size_t PMIN_FLOATS = (size_t)NS2 * NBC * Nn;

__global__ __launch_bounds__(256) void chamfer_partial(
    const float* __restrict__ X,   // output_points [8][4096][3]
    const float* __restrict__ Y,   // target_points [8][4096][3]
    float* __restrict__ pmin)
{
    __shared__ float4 ldsB[BCHUNK];   // 16 KB

    const int at    = blockIdx.x;     // A tile   0..3
    const int bc    = blockIdx.y;     // B chunk  0..3
    const int z     = blockIdx.z;     // dir*8 + slice, 0..15
    const int slice = z & 7;
    const int dir   = z >> 3;
    const int tid   = threadIdx.x;

    const float* A  = (dir == 0 ? X : Y) + slice * (Nn * 3);
    const float* Bp = (dir == 0 ? Y : X) + slice * (Mn * 3) + bc * (BCHUNK * 3);

    // Register-block 4 A-points per thread
    float ax[APT], ay[APT], az[APT], acc[APT];
    #pragma unroll
    for (int j = 0; j < APT; ++j) {
        const int n = at * ATILE + j * 256 + tid;
        ax[j] = A[n * 3 + 0];
        ay[j] = A[n * 3 + 1];
        az[j] = A[n * 3 + 2];
        acc[j] = 3.4e38f;
    }

    // Stage B chunk into LDS as float4 (one ds_read_b128 broadcast per point)
    for (int p = tid; p < BCHUNK; p += 256) {
        ldsB[p] = make_float4(Bp[p * 3 + 0], Bp[p * 3 + 1], Bp[p * 3 + 2], 0.0f);
    }
    __syncthreads();

    // 2 B-points x 4 A-points per iteration: 2 ds_read_b128 + 52 pair-VALU ops
    #pragma unroll 4
    for (int m = 0; m < BCHUNK; m += 2) {
        float4 b0 = ldsB[m + 0];
        float4 b1 = ldsB[m + 1];
        #pragma unroll
        for (int j = 0; j < APT; ++j) {
            float dx0 = ax[j] - b0.x, dy0 = ay[j] - b0.y, dz0 = az[j] - b0.z;
            float d0  = dx0 * dx0 + dy0 * dy0 + dz0 * dz0;
            float dx1 = ax[j] - b1.x, dy1 = ay[j] - b1.y, dz1 = az[j] - b1.z;
            float d1  = dx1 * dx1 + dy1 * dy1 + dz1 * dz1;
            acc[j] = fminf(acc[j], fminf(d0, d1));   // -> v_min3_f32
        }
    }

    // Coalesced partial-min store: pmin[z][bc][at*1024 + j*256 + tid]
    float* dst = pmin + ((size_t)z * NBC + bc) * Nn + at * ATILE;
    #pragma unroll
    for (int j = 0; j < APT; ++j) dst[j * 256 + tid] = acc[j];
}

__global__ __launch_bounds__(256) void chamfer_combine(
    const float* __restrict__ pmin, float* __restrict__ sums)
{
    const int z   = blockIdx.x;       // 0..15
    const int tid = threadIdx.x;
    const float* p = pmin + (size_t)z * NBC * Nn;

    float s = 0.0f;
    for (int i = tid; i < Nn; i += 256) {
        float m = fminf(fminf(p[0 * Nn + i], p[1 * Nn + i]),
                        fminf(p[2 * Nn + i], p[3 * Nn + i]));
        s += m;
    }

    // Deterministic reduction: shuffle tree + fixed-order wave combine
    s += __shfl_down(s, 32);
    s += __shfl_down(s, 16);
    s += __shfl_down(s, 8);
    s += __shfl_down(s, 4);
    s += __shfl_down(s, 2);
    s += __shfl_down(s, 1);

    __shared__ float red[4];
    if ((tid & 63) == 0) red[tid >> 6] = s;
    __syncthreads();
    if (tid == 0) sums[z] = red[0] + red[1] + red[2] + red[3];
}

__global__ __launch_bounds__(64) void chamfer_finalize(
    const float* __restrict__ sums, float* __restrict__ out)
{
    const int tid = threadIdx.x;
    // sums[z]: z = dir*8 + (b*4 + s), sum over A-points of min dist
    // out[0..3]  = chamfer_distances[s] = mean_b combined[b][s]
    // out[4..11] = chamfer_distances_tensor[s][b] = combined[b][s]
    if (tid < 8) {
        const int s = tid >> 1, b = tid & 1;
        const int l = b * Sn + s;
        out[4 + s * 2 + b] = sums[l] * (1.0f / Nn) + sums[8 + l] * (1.0f / Mn);
    } else if (tid < 12) {
        const int s = tid - 8;
        float c0 = sums[0 * Sn + s] * (1.0f / Nn) + sums[8 + 0 * Sn + s] * (1.0f / Mn);
        float c1 = sums[1 * Sn + s] * (1.0f / Nn) + sums[8 + 1 * Sn + s] * (1.0f / Mn);
        out[s] = 0.5f * (c0 + c1);
    }
}

extern "C" void kernel_launch(void* const* d_in, const int* in_sizes, int n_in,
                              void* d_out, int out_size, void* d_ws, size_t ws_size,
                              hipStream_t stream) {
    const float* X = (const float*)d_in[0];   // output_points [2,4,4096,3]
    const float* Y = (const float*)d_in[1];   // target_points [2,4,4096,3]
    float* out  = (float*)d_out;              // 12 floats
    float* pmin = (float*)d_ws;               // [16][4][4096] partial mins
    float* sums = pmin + PMIN_FLOATS;         // [16]

    dim3 grid(NAT, NBC, NS2);                 // 4 x 4 x 16 = 256 blocks (1/CU)
    chamfer_partial<<<grid, 256, 0, stream>>>(X, Y, pmin);
    chamfer_combine<<<NS2, 256, 0, stream>>>(pmin, sums);
    chamfer_finalize<<<1, 64, 0, stream>>>(sums, out);
}

// Round 3
// 40.754 us; speedup vs baseline: 2.0405x; 1.6438x over previous
//
#include <hip/hip_runtime.h>

// Problem constants: B=2, S=4, N=M=4096, fp32 3D points.
constexpr int Sn = 4;
constexpr int Nn = 4096;
constexpr int Mn = 4096;
constexpr int NS2 = 16;               // (dir,slice): z = dir*8 + slice
constexpr int ATILE = 1024;           // A-points per block
constexpr int APT = ATILE / 256;      // 4 A-points per thread
constexpr int NAT = Nn / ATILE;       // 4

// Main config: BCHUNK=256 (4 KB LDS), NBC=16 -> grid 4*16*16=1024 blocks (4/CU)
// Fallback (small ws): BCHUNK=1024, NBC=4 -> grid 256 blocks, pmin 1 MB (proven fits)

template <int BCHUNK, int NBC>
__global__ __launch_bounds__(256) void chamfer_partial(
    const float* __restrict__ X,   // output_points [8][4096][3]
    const float* __restrict__ Y,   // target_points [8][4096][3]
    float* __restrict__ pmin)      // [NS2][NBC][Nn]
{
    __shared__ float4 ldsB[BCHUNK];

    const int at    = blockIdx.x;
    const int bc    = blockIdx.y;
    const int z     = blockIdx.z;
    const int slice = z & 7;
    const int dir   = z >> 3;
    const int tid   = threadIdx.x;

    const float* A  = (dir == 0 ? X : Y) + slice * (Nn * 3);
    const float* Bp = (dir == 0 ? Y : X) + slice * (Mn * 3) + bc * (BCHUNK * 3);

    // Register-block APT A-points; keep |a|^2 aside (doesn't affect argmin)
    float ax[APT], ay[APT], az[APT], a2[APT], acc[APT];
    #pragma unroll
    for (int j = 0; j < APT; ++j) {
        const int n = at * ATILE + j * 256 + tid;
        ax[j] = A[n * 3 + 0];
        ay[j] = A[n * 3 + 1];
        az[j] = A[n * 3 + 2];
        a2[j] = ax[j] * ax[j] + ay[j] * ay[j] + az[j] * az[j];
        acc[j] = 3.4e38f;
    }

    // Stage B chunk pre-transformed: (-2bx, -2by, -2bz, |b|^2)
    for (int p = tid; p < BCHUNK; p += 256) {
        float bx = Bp[p * 3 + 0], by = Bp[p * 3 + 1], bz = Bp[p * 3 + 2];
        ldsB[p] = make_float4(-2.0f * bx, -2.0f * by, -2.0f * bz,
                              bx * bx + by * by + bz * bz);
    }
    __syncthreads();

    // 3 FMA per pair + 1 v_min3 per 2 pairs; 2 ds_read_b128 per 2*APT pairs
    #pragma unroll 4
    for (int m = 0; m < BCHUNK; m += 2) {
        float4 b0 = ldsB[m + 0];
        float4 b1 = ldsB[m + 1];
        #pragma unroll
        for (int j = 0; j < APT; ++j) {
            float d0 = fmaf(ax[j], b0.x, fmaf(ay[j], b0.y, fmaf(az[j], b0.z, b0.w)));
            float d1 = fmaf(ax[j], b1.x, fmaf(ay[j], b1.y, fmaf(az[j], b1.z, b1.w)));
            acc[j] = fminf(acc[j], fminf(d0, d1));   // -> v_min3_f32
        }
    }

    // Coalesced store of partial mins (+|a|^2, constant across chunks)
    float* dst = pmin + ((size_t)z * NBC + bc) * Nn + at * ATILE;
    #pragma unroll
    for (int j = 0; j < APT; ++j) dst[j * 256 + tid] = acc[j] + a2[j];
}

template <int NBC>
__global__ __launch_bounds__(256) void chamfer_combine(
    const float* __restrict__ pmin, float* __restrict__ sums)
{
    const int z   = blockIdx.x;       // 0..15
    const int tid = threadIdx.x;
    const float* p = pmin + (size_t)z * NBC * Nn;

    float s = 0.0f;
    for (int i = tid; i < Nn; i += 256) {
        float m = p[i];
        #pragma unroll
        for (int bc = 1; bc < NBC; ++bc) m = fminf(m, p[(size_t)bc * Nn + i]);
        s += m;
    }

    s += __shfl_down(s, 32);
    s += __shfl_down(s, 16);
    s += __shfl_down(s, 8);
    s += __shfl_down(s, 4);
    s += __shfl_down(s, 2);
    s += __shfl_down(s, 1);

    __shared__ float red[4];
    if ((tid & 63) == 0) red[tid >> 6] = s;
    __syncthreads();
    if (tid == 0) sums[z] = red[0] + red[1] + red[2] + red[3];
}

__global__ __launch_bounds__(64) void chamfer_finalize(
    const float* __restrict__ sums, float* __restrict__ out)
{
    const int tid = threadIdx.x;
    // sums[z]: z = dir*8 + (b*4 + s)
    // out[0..3]  = chamfer_distances[s] = mean_b combined[b][s]
    // out[4..11] = chamfer_distances_tensor[s][b] = combined[b][s]
    if (tid < 8) {
        const int s = tid >> 1, b = tid & 1;
        const int l = b * Sn + s;
        out[4 + s * 2 + b] = sums[l] * (1.0f / Nn) + sums[8 + l] * (1.0f / Mn);
    } else if (tid < 12) {
        const int s = tid - 8;
        float c0 = sums[0 * Sn + s] * (1.0f / Nn) + sums[8 + 0 * Sn + s] * (1.0f / Mn);
        float c1 = sums[1 * Sn + s] * (1.0f / Nn) + sums[8 + 1 * Sn + s] * (1.0f / Mn);
        out[s] = 0.5f * (c0 + c1);
    }
}

extern "C" void kernel_launch(void* const* d_in, const int* in_sizes, int n_in,
                              void* d_out, int out_size, void* d_ws, size_t ws_size,
                              hipStream_t stream) {
    const float* X = (const float*)d_in[0];   // output_points [2,4,4096,3]
    const float* Y = (const float*)d_in[1];   // target_points [2,4,4096,3]
    float* out  = (float*)d_out;              // 12 floats
    float* pmin = (float*)d_ws;

    const size_t need_main = ((size_t)NS2 * 16 * Nn + 64) * sizeof(float);

    if (ws_size >= need_main) {
        constexpr int NBC = 16, BCHUNK = Mn / NBC;           // 16 x 256
        float* sums = pmin + (size_t)NS2 * NBC * Nn;
        dim3 grid(NAT, NBC, NS2);                             // 1024 blocks (4/CU)
        chamfer_partial<BCHUNK, NBC><<<grid, 256, 0, stream>>>(X, Y, pmin);
        chamfer_combine<NBC><<<NS2, 256, 0, stream>>>(pmin, sums);
        chamfer_finalize<<<1, 64, 0, stream>>>(sums, out);
    } else {
        constexpr int NBC = 4, BCHUNK = Mn / NBC;             // 4 x 1024 (1 MB, proven)
        float* sums = pmin + (size_t)NS2 * NBC * Nn;
        dim3 grid(NAT, NBC, NS2);                             // 256 blocks
        chamfer_partial<BCHUNK, NBC><<<grid, 256, 0, stream>>>(X, Y, pmin);
        chamfer_combine<NBC><<<NS2, 256, 0, stream>>>(pmin, sums);
        chamfer_finalize<<<1, 64, 0, stream>>>(sums, out);
    }
}

// Round 4
// 34.710 us; speedup vs baseline: 2.3958x; 1.1741x over previous
//
#include <hip/hip_runtime.h>

// Problem constants: B=2, S=4, N=M=4096, fp32 3D points.
constexpr int Sn = 4;
constexpr int Nn = 4096;
constexpr int Mn = 4096;
constexpr int NS2 = 16;               // (dir,slice): z = dir*8 + slice
constexpr int CH  = 8;                // combine-kernel i-range split

// pmin layout: float [NS2][NBC][Nn]; then sums2[NS2][CH]

template <int APT, int NBC>
__global__ __launch_bounds__(256) void chamfer_partial(
    const float* __restrict__ X,   // output_points [8][4096][3]
    const float* __restrict__ Y,   // target_points [8][4096][3]
    float* __restrict__ pmin)      // [NS2][NBC][Nn]
{
    constexpr int BCHUNK = Mn / NBC;
    constexpr int ATILE  = APT * 256;

    __shared__ float4 ldsB[BCHUNK];

    const int at    = blockIdx.x;
    const int bc    = blockIdx.y;
    const int z     = blockIdx.z;
    const int slice = z & 7;
    const int dir   = z >> 3;
    const int tid   = threadIdx.x;

    const float* A  = (dir == 0 ? X : Y) + slice * (Nn * 3);
    const float* Bp = (dir == 0 ? Y : X) + slice * (Mn * 3) + bc * (BCHUNK * 3);

    // Register-block APT A-points; |a|^2 kept aside (doesn't affect argmin)
    float ax[APT], ay[APT], az[APT], a2[APT], acc[APT];
    #pragma unroll
    for (int j = 0; j < APT; ++j) {
        const int n = at * ATILE + j * 256 + tid;
        ax[j] = A[n * 3 + 0];
        ay[j] = A[n * 3 + 1];
        az[j] = A[n * 3 + 2];
        a2[j] = ax[j] * ax[j] + ay[j] * ay[j] + az[j] * az[j];
        acc[j] = 3.4e38f;
    }

    // Stage B chunk pre-transformed: (-2bx, -2by, -2bz, |b|^2)
    for (int p = tid; p < BCHUNK; p += 256) {
        float bx = Bp[p * 3 + 0], by = Bp[p * 3 + 1], bz = Bp[p * 3 + 2];
        ldsB[p] = make_float4(-2.0f * bx, -2.0f * by, -2.0f * bz,
                              bx * bx + by * by + bz * bz);
    }
    __syncthreads();

    // 2 ds_read_b128 amortized over 2*APT pairs; 3 FMA/pair + v_min3 per 2 pairs
    #pragma unroll 4
    for (int m = 0; m < BCHUNK; m += 2) {
        float4 b0 = ldsB[m + 0];
        float4 b1 = ldsB[m + 1];
        #pragma unroll
        for (int j = 0; j < APT; ++j) {
            float d0 = fmaf(ax[j], b0.x, fmaf(ay[j], b0.y, fmaf(az[j], b0.z, b0.w)));
            float d1 = fmaf(ax[j], b1.x, fmaf(ay[j], b1.y, fmaf(az[j], b1.z, b1.w)));
            acc[j] = fminf(acc[j], fminf(d0, d1));   // -> v_min3_f32
        }
    }

    // Coalesced store of partial mins (+|a|^2, constant across chunks)
    float* dst = pmin + ((size_t)z * NBC + bc) * Nn + at * ATILE;
    #pragma unroll
    for (int j = 0; j < APT; ++j) dst[j * 256 + tid] = acc[j] + a2[j];
}

template <int NBC>
__global__ __launch_bounds__(256) void chamfer_combine(
    const float* __restrict__ pmin, float* __restrict__ sums2)  // sums2[NS2][CH]
{
    const int z   = blockIdx.x;       // 0..15
    const int c   = blockIdx.y;       // 0..CH-1
    const int tid = threadIdx.x;
    constexpr int SPAN = Nn / CH;     // 512

    const float* p = pmin + (size_t)z * NBC * Nn;

    float s = 0.0f;
    for (int i = c * SPAN + tid; i < (c + 1) * SPAN; i += 256) {
        float m = p[i];
        #pragma unroll
        for (int bc = 1; bc < NBC; ++bc) m = fminf(m, p[(size_t)bc * Nn + i]);
        s += m;
    }

    s += __shfl_down(s, 32);
    s += __shfl_down(s, 16);
    s += __shfl_down(s, 8);
    s += __shfl_down(s, 4);
    s += __shfl_down(s, 2);
    s += __shfl_down(s, 1);

    __shared__ float red[4];
    if ((tid & 63) == 0) red[tid >> 6] = s;
    __syncthreads();
    if (tid == 0) sums2[z * CH + c] = red[0] + red[1] + red[2] + red[3];
}

__global__ __launch_bounds__(64) void chamfer_finalize(
    const float* __restrict__ sums2, float* __restrict__ out)
{
    const int tid = threadIdx.x;
    // total[z] = sum_c sums2[z][c]; z = dir*8 + (b*4 + s)
    __shared__ float tot[NS2];
    if (tid < NS2) {
        float t = 0.0f;
        #pragma unroll
        for (int c = 0; c < CH; ++c) t += sums2[tid * CH + c];
        tot[tid] = t;
    }
    __syncthreads();
    if (tid < 8) {
        const int s = tid >> 1, b = tid & 1;
        const int l = b * Sn + s;
        out[4 + s * 2 + b] = tot[l] * (1.0f / Nn) + tot[8 + l] * (1.0f / Mn);
    } else if (tid < 12) {
        const int s = tid - 8;
        float c0 = tot[0 * Sn + s] * (1.0f / Nn) + tot[8 + 0 * Sn + s] * (1.0f / Mn);
        float c1 = tot[1 * Sn + s] * (1.0f / Nn) + tot[8 + 1 * Sn + s] * (1.0f / Mn);
        out[s] = 0.5f * (c0 + c1);
    }
}

extern "C" void kernel_launch(void* const* d_in, const int* in_sizes, int n_in,
                              void* d_out, int out_size, void* d_ws, size_t ws_size,
                              hipStream_t stream) {
    const float* X = (const float*)d_in[0];   // output_points [2,4,4096,3]
    const float* Y = (const float*)d_in[1];   // target_points [2,4,4096,3]
    float* out  = (float*)d_out;              // 12 floats
    float* pmin = (float*)d_ws;

    const size_t need_main = ((size_t)NS2 * 32 * Nn + 256) * sizeof(float);

    if (ws_size >= need_main) {
        constexpr int APT = 8, NBC = 32;                      // 2 KB LDS, grid 2x32x16
        float* sums2 = pmin + (size_t)NS2 * NBC * Nn;
        dim3 grid(Nn / (APT * 256), NBC, NS2);                // 1024 blocks (4/CU)
        chamfer_partial<APT, NBC><<<grid, 256, 0, stream>>>(X, Y, pmin);
        chamfer_combine<NBC><<<dim3(NS2, CH), 256, 0, stream>>>(pmin, sums2);
        chamfer_finalize<<<1, 64, 0, stream>>>(sums2, out);
    } else {
        constexpr int APT = 4, NBC = 4;                       // 1 MB pmin fallback
        float* sums2 = pmin + (size_t)NS2 * NBC * Nn;
        dim3 grid(Nn / (APT * 256), NBC, NS2);                // 256 blocks
        chamfer_partial<APT, NBC><<<grid, 256, 0, stream>>>(X, Y, pmin);
        chamfer_combine<NBC><<<dim3(NS2, CH), 256, 0, stream>>>(pmin, sums2);
        chamfer_finalize<<<1, 64, 0, stream>>>(sums2, out);
    }
}